// Round 11
// baseline (120.662 us; speedup 1.0000x reference)
//
#include <hip/hip_runtime.h>
#include <math.h>

#define KC 8
#define DD 16
#define BLK 256

typedef short short8 __attribute__((ext_vector_type(8)));    // 8 bf16 (4 VGPRs)
typedef float floatx16 __attribute__((ext_vector_type(16))); // 32x32 MFMA acc

__device__ __forceinline__ unsigned asu(float x) { return __float_as_uint(x); }

// ---------------------------------------------------------------------------
// FUSED kernel, R11 = R9 (correct on all launches) minus the spills.
// R9 failed perf because __launch_bounds__(256,4) made the allocator pick a
// 64-VGPR budget -> xc/rowA spilled to scratch (70 MB writes, 20+ us).
// Fixes: (1) __launch_bounds__(BLK) only -- allocator free to use ~100 VGPRs;
// (2) Cholesky runs IN-PLACE (l[] overwrites a[] as it's produced) to cut
// phase-1 liveness; (3) phase 2 is R10's hoisted/unrolled MFMA body reading
// fragments from LDS; (4) fast __expf/__logf in the tiny epilogue.
// All 256 threads run prep redundantly (waves 2-3 duplicate waves 0-1 bit-
// exactly; duplicate LDS stores of identical bytes are benign) -- zero
// divergence anywhere near barriers.
// ---------------------------------------------------------------------------
__global__ __launch_bounds__(BLK) void gmm_fused(
    const float* __restrict__ data,
    const float* __restrict__ logits,
    const float* __restrict__ means,
    const float* __restrict__ scales,
    float* __restrict__ out, int N)
{
    __shared__ float Ash[KC][DD][DD + 1];        // transpose scratch
    __shared__ uint4 sAH[4 * 64];                // A-frag hi
    __shared__ uint4 sAL[4 * 64];                // A-frag lo
    __shared__ __align__(16) float sBF[128];     // -b acc-init (C-layout)
    __shared__ float sC[KC];                     // per-comp constant

    const int tid  = threadIdx.x;
    const int lane = tid & 63;
    const int half = lane >> 5;
    const int wbase = blockIdx.x * BLK + (tid & ~63);

    // ================= phase 1: prep, ALL threads (no divergence) ==========
    const int k    = (tid >> 4) & 7;
    const int i    = tid & 15;
    const int base = lane & 48;

    float hld = 0.f;
    float xc[DD];
    {
        // S row i of comp k
        float srow[DD];
        {
            const float4* sp = (const float4*)(scales + (size_t)(k * DD + i) * DD);
#pragma unroll
            for (int q = 0; q < 4; ++q) {
                float4 v = sp[q];
                srow[4 * q + 0] = v.x; srow[4 * q + 1] = v.y;
                srow[4 * q + 2] = v.z; srow[4 * q + 3] = v.w;
            }
        }

        // cov row i via shfl
        float a[DD];
#pragma unroll
        for (int j = 0; j < DD; ++j) a[j] = 0.f;
#pragma unroll
        for (int d = 0; d < DD; ++d) {
            float sid = srow[d];
#pragma unroll
            for (int j = 0; j < DD; ++j) {
                float sjd = __shfl(srow[d], base + j, 64);
                a[j] = fmaf(sid, sjd, a[j]);
            }
        }

        // right-looking Cholesky IN-PLACE: a[j] becomes L[i][j] at stage j
        // (a[j] is dead as cov the moment l_ij is computed; trailing updates
        // only touch a[c], c>j) -> phase-1 liveness stays ~32 floats.
#pragma unroll
        for (int j = 0; j < DD; ++j) {
            float ajj = __shfl(a[j], base + j, 64);   // updated diag
            float ljj = sqrtf(ajj);
            hld += __logf(ljj);
            float lij = (i < j) ? 0.f : (a[j] / ljj);
            a[j] = lij;                                // a[j] := L[i][j]
#pragma unroll
            for (int c = j + 1; c < DD; ++c) {
                float lcj = __shfl(lij, base + c, 64); // L[c][j] from lane c
                a[c] = fmaf(-lij, lcj, a[c]);
            }
        }

        // invert L: thread (k,i) -> column i of A = L^{-1} (a[] now holds L row i)
#pragma unroll
        for (int r = 0; r < DD; ++r) {
            float s = (r == i) ? 1.f : 0.f;
#pragma unroll
            for (int t = 0; t < DD; ++t) {
                if (t < r) {
                    float lrt = __shfl(a[t], base + r, 64);
                    s = fmaf(-lrt, xc[t], s);
                }
            }
            float lrr = __shfl(a[r], base + r, 64);
            xc[r] = (r < i) ? 0.f : (s / lrr);
        }
    }

    // transpose columns->rows via LDS (duplicate writers, same bytes)
#pragma unroll
    for (int r = 0; r < DD; ++r) Ash[k][r][i] = xc[r];
    __syncthreads();

    {
        float rowA[DD];
        float bb = 0.f;
#pragma unroll
        for (int j = 0; j < DD; ++j) {
            float aij = Ash[k][i][j];
            rowA[j] = aij;
            bb = fmaf(aij, means[k * DD + j], bb);
        }

        const int P = k >> 1;
        const int m = (k & 1) * 16 + i;
#pragma unroll
        for (int h = 0; h < 2; ++h) {
            unsigned dh[4], dl[4];
#pragma unroll
            for (int jj = 0; jj < 4; ++jj) {
                float e = rowA[h * 8 + 2 * jj];
                float o = rowA[h * 8 + 2 * jj + 1];
                unsigned he = asu(e) & 0xFFFF0000u, ho = asu(o) & 0xFFFF0000u;
                float re = e - __uint_as_float(he);
                float ro = o - __uint_as_float(ho);
                dh[jj] = (he >> 16) | ho;
                dl[jj] = ((asu(re) & 0xFFFF0000u) >> 16) | (asu(ro) & 0xFFFF0000u);
            }
            sAH[P * 64 + h * 32 + m] = make_uint4(dh[0], dh[1], dh[2], dh[3]);
            sAL[P * 64 + h * 32 + m] = make_uint4(dl[0], dl[1], dl[2], dl[3]);
        }

        {
            const int h = (m >> 2) & 1;
            const int t = (m & 3) | ((m >> 3) << 2);
            sBF[P * 32 + h * 16 + t] = -bb;
        }

        if (i == 0) {
            float mxl = logits[0];
            for (int t = 1; t < KC; ++t) mxl = fmaxf(mxl, logits[t]);
            float se = 0.f;
            for (int t = 0; t < KC; ++t) se += __expf(logits[t] - mxl);
            float lse = mxl + __logf(se);
            const float log2pi = 1.8378770664093453f;
            sC[k] = (logits[k] - lse) - hld - 0.5f * DD * log2pi;
        }
    }
    __syncthreads();

    // ================= phase 2: MFMA pipeline (R10 body, LDS operands) =====
    short8 ah[4], al[4];
#pragma unroll
    for (int P = 0; P < 4; ++P) {
        ah[P] = __builtin_bit_cast(short8, sAH[P * 64 + lane]);
        al[P] = __builtin_bit_cast(short8, sAL[P * 64 + lane]);
    }
    float ck[KC];
#pragma unroll
    for (int kk = 0; kk < KC; ++kk) ck[kk] = sC[kk];

    short8 bh[2], bl[2];
#pragma unroll
    for (int s = 0; s < 2; ++s) {
        int p = wbase + s * 32 + (lane & 31);
        p = p < N ? p : N - 1;
        const float4* xp = (const float4*)(data + (size_t)p * DD + half * 8);
        float4 v0 = xp[0], v1 = xp[1];
        float xs[8] = {v0.x, v0.y, v0.z, v0.w, v1.x, v1.y, v1.z, v1.w};
        unsigned dh[4], dl[4];
#pragma unroll
        for (int jj = 0; jj < 4; ++jj) {
            float e = xs[2 * jj], o = xs[2 * jj + 1];
            unsigned he = asu(e) & 0xFFFF0000u, ho = asu(o) & 0xFFFF0000u;
            float re = e - __uint_as_float(he);
            float ro = o - __uint_as_float(ho);
            dh[jj] = __builtin_amdgcn_perm(ho, he, 0x07060302u);
            dl[jj] = __builtin_amdgcn_perm(asu(ro), asu(re), 0x07060302u);
        }
        bh[s] = __builtin_bit_cast(short8, make_uint4(dh[0], dh[1], dh[2], dh[3]));
        bl[s] = __builtin_bit_cast(short8, make_uint4(dl[0], dl[1], dl[2], dl[3]));
    }

    float mx = -1e30f, sum = 0.f;

#pragma unroll
    for (int P = 0; P < 4; ++P) {
        const float4* bfp = (const float4*)(sBF + P * 32 + half * 16);
        float4 b0 = bfp[0], b1 = bfp[1], b2 = bfp[2], b3 = bfp[3];

        float me[2], mo[2];
#pragma unroll
        for (int s = 0; s < 2; ++s) {
            floatx16 acc = {b0.x, b0.y, b0.z, b0.w, b1.x, b1.y, b1.z, b1.w,
                            b2.x, b2.y, b2.z, b2.w, b3.x, b3.y, b3.z, b3.w};
            acc = __builtin_amdgcn_mfma_f32_32x32x16_bf16(ah[P], bh[s], acc, 0, 0, 0);
            acc = __builtin_amdgcn_mfma_f32_32x32x16_bf16(ah[P], bl[s], acc, 0, 0, 0);
            acc = __builtin_amdgcn_mfma_f32_32x32x16_bf16(al[P], bh[s], acc, 0, 0, 0);
            float se = acc[0] * acc[0], so = acc[8] * acc[8];
#pragma unroll
            for (int t = 1; t < 8; ++t) {
                se = fmaf(acc[t], acc[t], se);
                so = fmaf(acc[t + 8], acc[t + 8], so);
            }
            me[s] = se + __shfl_xor(se, 32, 64);
            mo[s] = so + __shfl_xor(so, 32, 64);
        }

        float mE = half ? me[1] : me[0];
        float mO = half ? mo[1] : mo[0];

        float lpk = fmaf(-0.5f, mE, ck[2 * P]);
        float nm = fmaxf(mx, lpk);
        sum = sum * __expf(mx - nm) + __expf(lpk - nm);
        mx = nm;

        lpk = fmaf(-0.5f, mO, ck[2 * P + 1]);
        nm = fmaxf(mx, lpk);
        sum = sum * __expf(mx - nm) + __expf(lpk - nm);
        mx = nm;
    }

    const int id = wbase + lane;
    if (id < N) out[id] = mx + __logf(sum);
}

extern "C" void kernel_launch(void* const* d_in, const int* in_sizes, int n_in,
                              void* d_out, int out_size, void* d_ws, size_t ws_size,
                              hipStream_t stream) {
    const float* data   = (const float*)d_in[0];
    const float* logits = (const float*)d_in[1];
    const float* means  = (const float*)d_in[2];
    const float* scales = (const float*)d_in[3];
    float* out = (float*)d_out;
    const int N = in_sizes[0] / DD;

    const int nblk = (N + BLK - 1) / BLK;
    gmm_fused<<<nblk, BLK, 0, stream>>>(data, logits, means, scales, out, N);
}

// Round 15
// 90.592 us; speedup vs baseline: 1.3319x; 1.3319x over previous
//
#include <hip/hip_runtime.h>
#include <math.h>

#define KC 8
#define DD 16
#define BLK 256

typedef short short8 __attribute__((ext_vector_type(8)));    // 8 bf16 (4 VGPRs)
typedef float floatx16 __attribute__((ext_vector_type(16))); // 32x32 MFMA acc

__device__ __forceinline__ unsigned asu(float x) { return __float_as_uint(x); }

// ---------------------------------------------------------------------------
// Kernel 1: prep (R10, proven replay-stable): shuffle Cholesky + inversion,
// emits
//  - AH2/AL2: A-fragments of [L^-1_{2P}; L^-1_{2P+1}] (32x16), bf16 hi/lo
//  - BF: -b in 32x32 C-layout (acc-init)
//  - Cout: log mix weight - sum log L_ii - D/2 log2pi
// ---------------------------------------------------------------------------
__global__ __launch_bounds__(128) void gmm_prep(
    const float* __restrict__ logits,
    const float* __restrict__ means,
    const float* __restrict__ scales,
    uint4* __restrict__ AH2,    // [4 pairs][64 lanes]
    uint4* __restrict__ AL2,    // [4 pairs][64 lanes]
    float* __restrict__ BF,     // [4 pairs][2 halves][16]
    float* __restrict__ Cout)   // [KC]
{
    const int tid  = threadIdx.x;
    const int k    = tid >> 4;
    const int i    = tid & 15;
    const int lane = tid & 63;
    const int base = lane & 48;

    float srow[DD];
    {
        const float4* sp = (const float4*)(scales + (size_t)(k * DD + i) * DD);
#pragma unroll
        for (int q = 0; q < 4; ++q) {
            float4 v = sp[q];
            srow[4 * q + 0] = v.x; srow[4 * q + 1] = v.y;
            srow[4 * q + 2] = v.z; srow[4 * q + 3] = v.w;
        }
    }

    float a[DD];
#pragma unroll
    for (int j = 0; j < DD; ++j) a[j] = 0.f;
#pragma unroll
    for (int d = 0; d < DD; ++d) {
        float sid = srow[d];
#pragma unroll
        for (int j = 0; j < DD; ++j) {
            float sjd = __shfl(srow[d], base + j, 64);
            a[j] = fmaf(sid, sjd, a[j]);
        }
    }

    float l[DD];
    float hld = 0.f;
#pragma unroll
    for (int j = 0; j < DD; ++j) {
        float ajj = __shfl(a[j], base + j, 64);
        float ljj = sqrtf(ajj);
        hld += logf(ljj);
        float lij = (i < j) ? 0.f : (a[j] / ljj);
        l[j] = lij;
#pragma unroll
        for (int c = j + 1; c < DD; ++c) {
            float lcj = __shfl(l[j], base + c, 64);
            a[c] = fmaf(-lij, lcj, a[c]);
        }
    }

    float xc[DD];
#pragma unroll
    for (int r = 0; r < DD; ++r) {
        float s = (r == i) ? 1.f : 0.f;
#pragma unroll
        for (int t = 0; t < DD; ++t) {
            if (t < r) {
                float lrt = __shfl(l[t], base + r, 64);
                s = fmaf(-lrt, xc[t], s);
            }
        }
        float lrr = __shfl(l[r], base + r, 64);
        xc[r] = (r < i) ? 0.f : (s / lrr);
    }

    __shared__ float Ash[KC][DD][DD + 1];
#pragma unroll
    for (int r = 0; r < DD; ++r) Ash[k][r][i] = xc[r];
    __syncthreads();

    float rowA[DD];
    float bb = 0.f;
#pragma unroll
    for (int j = 0; j < DD; ++j) {
        float aij = Ash[k][i][j];
        rowA[j] = aij;
        bb = fmaf(aij, means[k * DD + j], bb);
    }

    const int P = k >> 1;
    const int m = (k & 1) * 16 + i;
#pragma unroll
    for (int h = 0; h < 2; ++h) {
        unsigned dh[4], dl[4];
#pragma unroll
        for (int jj = 0; jj < 4; ++jj) {
            float e = rowA[h * 8 + 2 * jj];
            float o = rowA[h * 8 + 2 * jj + 1];
            unsigned he = asu(e) & 0xFFFF0000u, ho = asu(o) & 0xFFFF0000u;
            float re = e - __uint_as_float(he);
            float ro = o - __uint_as_float(ho);
            dh[jj] = (he >> 16) | ho;
            dl[jj] = ((asu(re) & 0xFFFF0000u) >> 16) | (asu(ro) & 0xFFFF0000u);
        }
        AH2[P * 64 + h * 32 + m] = make_uint4(dh[0], dh[1], dh[2], dh[3]);
        AL2[P * 64 + h * 32 + m] = make_uint4(dl[0], dl[1], dl[2], dl[3]);
    }

    {
        const int h = (m >> 2) & 1;
        const int t = (m & 3) | ((m >> 3) << 2);
        BF[P * 32 + h * 16 + t] = -bb;
    }

    if (i == 0) {
        float mx = logits[0];
        for (int t = 1; t < KC; ++t) mx = fmaxf(mx, logits[t]);
        float se = 0.f;
        for (int t = 0; t < KC; ++t) se += expf(logits[t] - mx);
        float lse = mx + logf(se);
        const float log2pi = 1.8378770664093453f;
        Cout[k] = (logits[k] - lse) - hld - 0.5f * DD * log2pi;
    }
}

// ---------------------------------------------------------------------------
// Kernel 2 (R10, proven replay-stable): hoisted A-fragments + fully-unrolled
// P-loop; 64 points/wave (2 sets of 32); online logsumexp.
// ---------------------------------------------------------------------------
__global__ __launch_bounds__(BLK, 4) void gmm_lp(
    const float* __restrict__ data,
    const uint4* __restrict__ AH2,
    const uint4* __restrict__ AL2,
    const float* __restrict__ BF,
    const float* __restrict__ Cg,
    float* __restrict__ out, int N)
{
    const int tid  = threadIdx.x;
    const int lane = tid & 63;
    const int half = lane >> 5;
    const int wbase = blockIdx.x * BLK + (tid & ~63);

    // ---- hoisted operand loads (issue first, all independent) ----
    short8 ah[4], al[4];
#pragma unroll
    for (int P = 0; P < 4; ++P) {
        ah[P] = __builtin_bit_cast(short8, AH2[P * 64 + lane]);
        al[P] = __builtin_bit_cast(short8, AL2[P * 64 + lane]);
    }
    float ck[KC];
#pragma unroll
    for (int k = 0; k < KC; ++k) ck[k] = Cg[k];   // uniform -> scalar loads

    // ---- data load + bf16 hi/lo split (B-fragment layout by construction) --
    short8 bh[2], bl[2];
#pragma unroll
    for (int s = 0; s < 2; ++s) {
        int p = wbase + s * 32 + (lane & 31);
        p = p < N ? p : N - 1;
        const float4* xp = (const float4*)(data + (size_t)p * DD + half * 8);
        float4 v0 = xp[0], v1 = xp[1];
        float xs[8] = {v0.x, v0.y, v0.z, v0.w, v1.x, v1.y, v1.z, v1.w};
        unsigned dh[4], dl[4];
#pragma unroll
        for (int jj = 0; jj < 4; ++jj) {
            float e = xs[2 * jj], o = xs[2 * jj + 1];
            unsigned he = asu(e) & 0xFFFF0000u, ho = asu(o) & 0xFFFF0000u;
            float re = e - __uint_as_float(he);
            float ro = o - __uint_as_float(ho);
            dh[jj] = __builtin_amdgcn_perm(ho, he, 0x07060302u);
            dl[jj] = __builtin_amdgcn_perm(asu(ro), asu(re), 0x07060302u);
        }
        bh[s] = __builtin_bit_cast(short8, make_uint4(dh[0], dh[1], dh[2], dh[3]));
        bl[s] = __builtin_bit_cast(short8, make_uint4(dl[0], dl[1], dl[2], dl[3]));
    }

    float mx = -1e30f, sum = 0.f;

#pragma unroll
    for (int P = 0; P < 4; ++P) {
        const float4* bfp = (const float4*)(BF + P * 32 + half * 16);
        float4 b0 = bfp[0], b1 = bfp[1], b2 = bfp[2], b3 = bfp[3];

        float me[2], mo[2];
#pragma unroll
        for (int s = 0; s < 2; ++s) {
            floatx16 acc = {b0.x, b0.y, b0.z, b0.w, b1.x, b1.y, b1.z, b1.w,
                            b2.x, b2.y, b2.z, b2.w, b3.x, b3.y, b3.z, b3.w};
            acc = __builtin_amdgcn_mfma_f32_32x32x16_bf16(ah[P], bh[s], acc, 0, 0, 0);
            acc = __builtin_amdgcn_mfma_f32_32x32x16_bf16(ah[P], bl[s], acc, 0, 0, 0);
            acc = __builtin_amdgcn_mfma_f32_32x32x16_bf16(al[P], bh[s], acc, 0, 0, 0);
            float se = acc[0] * acc[0], so = acc[8] * acc[8];
#pragma unroll
            for (int t = 1; t < 8; ++t) {
                se = fmaf(acc[t], acc[t], se);
                so = fmaf(acc[t + 8], acc[t + 8], so);
            }
            me[s] = se + __shfl_xor(se, 32, 64);   // maha, comp 2P
            mo[s] = so + __shfl_xor(so, 32, 64);   // maha, comp 2P+1
        }

        float mE = half ? me[1] : me[0];
        float mO = half ? mo[1] : mo[0];

        float lpk = fmaf(-0.5f, mE, ck[2 * P]);
        float nm = fmaxf(mx, lpk);
        sum = sum * __expf(mx - nm) + __expf(lpk - nm);
        mx = nm;

        lpk = fmaf(-0.5f, mO, ck[2 * P + 1]);
        nm = fmaxf(mx, lpk);
        sum = sum * __expf(mx - nm) + __expf(lpk - nm);
        mx = nm;
    }

    const int id = wbase + lane;
    if (id < N) out[id] = mx + __logf(sum);
}

extern "C" void kernel_launch(void* const* d_in, const int* in_sizes, int n_in,
                              void* d_out, int out_size, void* d_ws, size_t ws_size,
                              hipStream_t stream) {
    const float* data   = (const float*)d_in[0];
    const float* logits = (const float*)d_in[1];
    const float* means  = (const float*)d_in[2];
    const float* scales = (const float*)d_in[3];
    float* out = (float*)d_out;
    const int N = in_sizes[0] / DD;

    uint4* AH2 = (uint4*)d_ws;             // 4*64 uint4 = 4 KB
    uint4* AL2 = AH2 + 4 * 64;             // 4 KB
    float* BF  = (float*)(AL2 + 4 * 64);   // 128 floats
    float* C   = BF + 128;                 // 8 floats

    gmm_prep<<<1, 128, 0, stream>>>(logits, means, scales, AH2, AL2, BF, C);
    const int nblk = (N + BLK - 1) / BLK;
    gmm_lp<<<nblk, BLK, 0, stream>>>(data, AH2, AL2, BF, C, out, N);
}